// Round 13
// baseline (28266.232 us; speedup 1.0000x reference)
//
#include <hip/hip_runtime.h>
#include <hip/hip_fp16.h>

// MC-LSTM persistent recurrence, v14: v11 topology (8 b-slices x 7 unit-shards,
// 56 WGs x 512 thr, agent-scope relaxed tagged-data) + sentinel-gated polling
// (bounded fast-gate; tag-verified payload remains the correctness path),
// out[] writes moved off the critical path, i-weight prefetch.

#define TT 2048
#define NBS 8
#define NUS 7
#define NWG 56
#define SPIN_CAP (1 << 16)

typedef _Float16 f16;
typedef _Float16 f16x8 __attribute__((ext_vector_type(8)));
typedef float f32x4 __attribute__((ext_vector_type(4)));

#define LD_RLX(p)   __hip_atomic_load((p), __ATOMIC_RELAXED, __HIP_MEMORY_SCOPE_AGENT)
#define ST_RLX(p,v) __hip_atomic_store((p), (v), __ATOMIC_RELAXED, __HIP_MEMORY_SCOPE_AGENT)

static __device__ __forceinline__ unsigned packf16(float v, unsigned tag) {
  f16 h = (f16)v;
  unsigned short s;
  __builtin_memcpy(&s, &h, 2);
  return ((unsigned)s << 16) | (tag & 0xffffu);
}
static __device__ __forceinline__ float unpackf16(unsigned u) {
  unsigned short s = (unsigned short)(u >> 16);
  f16 h;
  __builtin_memcpy(&h, &s, 2);
  return (float)h;
}
static __device__ __forceinline__ float f16bits(unsigned short s) {
  f16 h;
  __builtin_memcpy(&h, &s, 2);
  return (float)h;
}
static __device__ __forceinline__ unsigned short f16of(float v) {
  f16 h = (f16)v;
  unsigned short s;
  __builtin_memcpy(&s, &h, 2);
  return s;
}

// ---- ws layout (bytes) ----
#define OFF_WH   0u
#define SZ_WH    (97u * 8192u * 2u)                    // fp16 weights [unit][h][g]
#define OFF_SLAB ((OFF_WH + SZ_WH + 255u) & ~255u)     // [2][8 bs][7 us][1024] u32
#define SZ_SLAB  (2u * NBS * NUS * 1024u * 4u)
#define OFF_NS   (OFF_SLAB + SZ_SLAB)                  // [2][8 bs] tagged u32
#define SZ_NS    (2u * NBS * 4u)
#define OFF_SENT (OFF_NS + SZ_NS)                      // [2][8 bs][32] u32 (128B/bs)
#define SZ_SENT  (2u * NBS * 32u * 4u)
#define ZERO_OFF OFF_SLAB
#define ZERO_LEN (SZ_SLAB + SZ_NS + SZ_SENT)

__global__ void prep_kernel(const float* __restrict__ Wi, const float* __restrict__ Wr,
                            const float* __restrict__ Wo, f16* __restrict__ Wh) {
  int idx = blockIdx.x * 256 + threadIdx.x;
  if (idx >= 97 * 8192) return;
  int g = idx & 127, h = (idx >> 7) & 63, r = idx >> 13;
  float v;
  if (r < 32)      v = Wi[g * 2048 + r * 64 + h];
  else if (r < 96) v = Wr[g * 4096 + (r - 32) * 64 + h];
  else             v = Wo[g * 64 + h];
  Wh[idx] = (f16)v;
}

__launch_bounds__(512, 1)
__global__ void mclstm_kernel(const float* __restrict__ xm, const float* __restrict__ xa,
                              const float* __restrict__ bi, const float* __restrict__ br,
                              const float* __restrict__ bo, const f16* __restrict__ Wh,
                              unsigned* __restrict__ slab, unsigned* __restrict__ nslab,
                              unsigned* __restrict__ sent, float* __restrict__ out) {
  const int j = blockIdx.x, tid = threadIdx.x;
  const int us = j % NUS, bs = j / NUS;
  const int w = tid >> 6, l = tid & 63, lr = l & 15, lk = l >> 4;
  const bool isO = (us == 6);
  const bool isIWG = (us < 2);  // us 0,1 -> i-units 0..31; us 2..5 -> r; us 6 -> o

  __shared__ unsigned short craw[16][88];  // raw c bits (this b-slice), padded rows
  __shared__ float pslab[8][1024];         // per-wave contrib partials
  __shared__ float nredL[8];
  __shared__ float invS;

  for (int i = tid; i < 16 * 88; i += 512) (&craw[0][0])[i] = 0;
  if (tid == 0) invS = 0.f;

  // ---- persistent weights in registers: 2 units per wave (us6 -> o unit 96) ----
  f16x8 Bf[2][4][4];
  float bu[2][4];
#pragma unroll
  for (int un = 0; un < 2; ++un) {
    int u = isO ? 96 : us * 16 + 2 * w + un;
#pragma unroll
    for (int ht = 0; ht < 4; ++ht) {
      int col = ht * 16 + lr;
      bu[un][ht] = (u < 32) ? bi[u * 64 + col]
                 : (u < 96) ? br[(u - 32) * 64 + col] : bo[col];
#pragma unroll
      for (int kk = 0; kk < 4; ++kk)
        Bf[un][ht][kk] = *(const f16x8*)(Wh + (size_t)u * 8192 + col * 128 + kk * 32 + lk * 8);
    }
  }

  const size_t xoff = (size_t)(bs * 16 + lr) * 32 + lk * 8;
  f32x4 xA0 = *(const f32x4*)(xm + xoff), xA1 = *(const f32x4*)(xm + xoff + 4);
  f32x4 xB0 = *(const f32x4*)(xa + xoff), xB1 = *(const f32x4*)(xa + xoff + 4);
  __syncthreads();

  float ov0 = 0.f, ov1 = 0.f, mn0 = 0.f, mn1 = 0.f, cn0 = 0.f, cn1 = 0.f;

  for (int t = 0; t <= TT; ++t) {
    // ---- (0) prefetch this step's i-einsum weights (overlaps the poll) ----
    float xw[2][4];
    if (isIWG && t < TT) {
      const float* xmtp = xm + (size_t)t * 4096;
#pragma unroll
      for (int rr = 0; rr < 4; ++rr) {
        const size_t ro = (size_t)(bs * 16 + lk * 4 + rr) * 32 + us * 16 + 2 * w;
        xw[0][rr] = xmtp[ro];
        xw[1][rr] = xmtp[ro + 1];
      }
    }

    // ---- phase 1: sentinel gate -> tag-verified payload; reduce; stage craw ----
    if (t > 0) {
      const unsigned want = (unsigned)t & 0xffffu;
      // bounded sentinel fast-gate (hint only; per-wave, lanes 0..6)
      {
        const unsigned* sb = sent + ((size_t)(t & 1) * NBS + bs) * 32;
        for (int it = 0; it < SPIN_CAP; ++it) {
          unsigned v = (l < NUS) ? LD_RLX(sb + l) : want;
          if (__all((int)((v & 0xffffu) == want))) break;
          __builtin_amdgcn_s_sleep(1);
        }
      }
      // tag-verified payload sweep (correctness-bearing; v11-proven live)
      const unsigned* base = slab + ((size_t)(t & 1) * NBS + bs) * (NUS * 1024);
      const int e0 = 2 * tid;
      unsigned pv[14];
      for (;;) {
#pragma unroll
        for (int c = 0; c < 7; ++c) {
          pv[c] = LD_RLX(base + c * 1024 + e0);
          pv[7 + c] = LD_RLX(base + c * 1024 + e0 + 1);
        }
        unsigned m = 0;
#pragma unroll
        for (int c = 0; c < 14; ++c) m |= (pv[c] ^ want) & 0xffffu;
        if (m == 0) break;
        __builtin_amdgcn_s_sleep(1);
      }
      mn0 = 0.f; mn1 = 0.f;
#pragma unroll
      for (int c = 0; c < 6; ++c) {
        mn0 += unpackf16(pv[c]);
        mn1 += unpackf16(pv[7 + c]);
      }
      ov0 = unpackf16(pv[6]);
      ov1 = unpackf16(pv[13]);
      cn0 = (1.0f - ov0) * mn0;
      cn1 = (1.0f - ov1) * mn1;
      const unsigned short h0 = f16of(cn0), h1 = f16of(cn1);
      const int b = e0 >> 6, h = e0 & 63;
      craw[b][h] = h0;
      craw[b][h + 1] = h1;
      if (isO) {  // norm publish ASAP (consumers poll it during their GEMM)
        float ns = fabsf(f16bits(h0)) + fabsf(f16bits(h1));
        ns += __shfl_xor(ns, 1, 64);
        ns += __shfl_xor(ns, 2, 64);
        ns += __shfl_xor(ns, 4, 64);
        ns += __shfl_xor(ns, 8, 64);
        ns += __shfl_xor(ns, 16, 64);
        ns += __shfl_xor(ns, 32, 64);
        if (l == 0) nredL[w] = ns;
        __syncthreads();
        if (tid == 0) {
          float nsum = 0.f;
#pragma unroll
          for (int p = 0; p < 8; ++p) nsum += nredL[p];
          ST_RLX(nslab + (t & 1) * NBS + bs, packf16(nsum, (unsigned)t));
        }
      }
    }
    if (t == TT) {
      if (isO) {  // final step's outputs
        const int e0 = 2 * tid, b = e0 >> 6, h = e0 & 63;
        const int bg = bs * 16 + b;
        out[(size_t)(t - 1) * 8192 + bg * 64 + h] = ov0 * mn0;
        out[(size_t)(t - 1) * 8192 + bg * 64 + h + 1] = ov1 * mn1;
        out[(size_t)(TT + t - 1) * 8192 + bg * 64 + h] = cn0;
        out[(size_t)(TT + t - 1) * 8192 + bg * 64 + h + 1] = cn1;
      }
      break;
    }
    __syncthreads();  // B1: craw staged

    // ---- phase 3: A-frags (raw c) + dual-accumulator GEMM ----
    f16x8 A0, A1, A2, A3;
#pragma unroll
    for (int i = 0; i < 4; ++i) {
      A0[i] = (f16)xA0[i]; A0[4 + i] = (f16)xA1[i];
      A1[i] = (f16)xB0[i]; A1[4 + i] = (f16)xB1[i];
    }
    {
      const unsigned short* cr = &craw[lr][0];
#pragma unroll
      for (int i = 0; i < 8; ++i) A2[i] = *(const f16*)&cr[lk * 8 + i];
#pragma unroll
      for (int i = 0; i < 8; ++i) A3[i] = *(const f16*)&cr[32 + lk * 8 + i];
    }
    if (t + 1 < TT) {
      const float* bx = xm + (size_t)(t + 1) * 4096 + xoff;
      const float* ba = xa + (size_t)(t + 1) * 4096 + xoff;
      xA0 = *(const f32x4*)bx; xA1 = *(const f32x4*)(bx + 4);
      xB0 = *(const f32x4*)ba; xB1 = *(const f32x4*)(ba + 4);
    }
    f32x4 aX[2][4], aC[2][4];
    if (!isO || w == 0) {
#pragma unroll
      for (int un = 0; un < 2; ++un)
#pragma unroll
        for (int ht = 0; ht < 4; ++ht) {
          f32x4 a = (f32x4){0.f, 0.f, 0.f, 0.f};
          a = __builtin_amdgcn_mfma_f32_16x16x32_f16(A0, Bf[un][ht][0], a, 0, 0, 0);
          a = __builtin_amdgcn_mfma_f32_16x16x32_f16(A1, Bf[un][ht][1], a, 0, 0, 0);
          aX[un][ht] = a;
          f32x4 c = (f32x4){0.f, 0.f, 0.f, 0.f};
          c = __builtin_amdgcn_mfma_f32_16x16x32_f16(A2, Bf[un][ht][2], c, 0, 0, 0);
          c = __builtin_amdgcn_mfma_f32_16x16x32_f16(A3, Bf[un][ht][3], c, 0, 0, 0);
          aC[un][ht] = c;
        }
    }

    // ---- phase 4: wave0 polls the 8 norm words (overlapped with GEMM) ----
    if (t > 0 && w == 0) {
      const unsigned want = (unsigned)t & 0xffffu;
      const unsigned* nsb = nslab + (t & 1) * NBS;
      unsigned v;
      for (;;) {
        v = (l < NBS) ? LD_RLX(nsb + l) : want;
        if (__all((int)((v & 0xffffu) == want))) break;
        __builtin_amdgcn_s_sleep(1);
      }
      float ns = (l < NBS) ? unpackf16(v) : 0.f;
      ns += __shfl_xor(ns, 1, 64);
      ns += __shfl_xor(ns, 2, 64);
      ns += __shfl_xor(ns, 4, 64);
      if (l == 0) invS = __builtin_amdgcn_rcpf(ns + 1e-5f);
    }
    __syncthreads();  // B2: invS visible
    const float inv = invS;

    // ---- phase 5: epilogue z = aX + inv*aC + b ----
    if (!isO) {
      float contrib[4][4];
#pragma unroll
      for (int ht = 0; ht < 4; ++ht)
#pragma unroll
        for (int rr = 0; rr < 4; ++rr) contrib[ht][rr] = 0.f;
#pragma unroll
      for (int un = 0; un < 2; ++un) {
        const int kidx = us * 16 + 2 * w + un - 32;  // valid for r-units only
#pragma unroll
        for (int rr = 0; rr < 4; ++rr) {
          const int b = lk * 4 + rr;
          float s4[4], sum = 0.f;
#pragma unroll
          for (int ht = 0; ht < 4; ++ht) {
            float z = aX[un][ht][rr] + inv * aC[un][ht][rr] + bu[un][ht];
            float sg = __builtin_amdgcn_rcpf(1.0f + __expf(-z));
            s4[ht] = sg;
            sum += sg;
          }
          float r4 = sum;
          r4 += __shfl_xor(r4, 1, 64);
          r4 += __shfl_xor(r4, 2, 64);
          r4 += __shfl_xor(r4, 4, 64);
          r4 += __shfl_xor(r4, 8, 64);
          float wr = isIWG ? xw[un][rr] : f16bits(craw[b][kidx]);
          float sc = wr * __builtin_amdgcn_rcpf(fmaxf(r4, 1e-12f));
#pragma unroll
          for (int ht = 0; ht < 4; ++ht) contrib[ht][rr] += s4[ht] * sc;
        }
      }
#pragma unroll
      for (int ht = 0; ht < 4; ++ht)
#pragma unroll
        for (int rr = 0; rr < 4; ++rr)
          pslab[w][(lk * 4 + rr) * 64 + ht * 16 + lr] = contrib[ht][rr];
    } else if (w == 0) {
#pragma unroll
      for (int ht = 0; ht < 4; ++ht)
#pragma unroll
        for (int rr = 0; rr < 4; ++rr) {
          float z = aX[0][ht][rr] + inv * aC[0][ht][rr] + bu[0][ht];
          pslab[0][(lk * 4 + rr) * 64 + ht * 16 + lr] =
              __builtin_amdgcn_rcpf(1.0f + __expf(-z));
        }
    }
    __syncthreads();  // B3: pslab complete

    // ---- phase 6: intra-WG sum -> tagged column store; then sentinel ----
    {
      const int e0 = 2 * tid;
      float v0, v1;
      if (!isO) {
        v0 = 0.f; v1 = 0.f;
#pragma unroll
        for (int p = 0; p < 8; ++p) {
          float2 pv2 = *(const float2*)&pslab[p][e0];
          v0 += pv2.x;
          v1 += pv2.y;
        }
      } else {
        float2 pv2 = *(const float2*)&pslab[0][e0];
        v0 = pv2.x;
        v1 = pv2.y;
      }
      const unsigned tg = (unsigned)(t + 1);
      unsigned* dst = slab + ((size_t)((t + 1) & 1) * NBS + bs) * (NUS * 1024) + us * 1024;
      ST_RLX(dst + e0, packf16(v0, tg));
      ST_RLX(dst + e0 + 1, packf16(v1, tg));
    }
    __syncthreads();  // B4: drains payload stores (per-wave vmcnt) + WAR on craw
    if (tid == 0)
      ST_RLX(sent + ((size_t)((t + 1) & 1) * NBS + bs) * 32 + us, (unsigned)(t + 1));

    // ---- out[] for step t-1 — fire-and-forget, drains during next poll ----
    if (isO && t > 0) {
      const int e0 = 2 * tid, b = e0 >> 6, h = e0 & 63;
      const int bg = bs * 16 + b;
      out[(size_t)(t - 1) * 8192 + bg * 64 + h] = ov0 * mn0;
      out[(size_t)(t - 1) * 8192 + bg * 64 + h + 1] = ov1 * mn1;
      out[(size_t)(TT + t - 1) * 8192 + bg * 64 + h] = cn0;
      out[(size_t)(TT + t - 1) * 8192 + bg * 64 + h + 1] = cn1;
    }
  }
}

extern "C" void kernel_launch(void* const* d_in, const int* in_sizes, int n_in,
                              void* d_out, int out_size, void* d_ws, size_t ws_size,
                              hipStream_t stream) {
  (void)in_sizes; (void)n_in; (void)out_size; (void)ws_size;
  const float* xm = (const float*)d_in[0];
  const float* xa = (const float*)d_in[1];
  const float* Wi = (const float*)d_in[2];
  const float* bi = (const float*)d_in[3];
  const float* Wr = (const float*)d_in[4];
  const float* br = (const float*)d_in[5];
  const float* Wo = (const float*)d_in[6];
  const float* bo = (const float*)d_in[7];

  char* ws = (char*)d_ws;
  f16* Wh         = (f16*)(ws + OFF_WH);
  unsigned* slab  = (unsigned*)(ws + OFF_SLAB);
  unsigned* nslab = (unsigned*)(ws + OFF_NS);
  unsigned* sent  = (unsigned*)(ws + OFF_SENT);

  // Tag hygiene across graph replays.
  hipMemsetAsync(ws + ZERO_OFF, 0, ZERO_LEN, stream);
  prep_kernel<<<(97 * 8192 + 255) / 256, 256, 0, stream>>>(Wi, Wr, Wo, Wh);
  mclstm_kernel<<<NWG, 512, 0, stream>>>(xm, xa, bi, br, bo, Wh, slab, nslab, sent,
                                         (float*)d_out);
}

// Round 14
// 17723.627 us; speedup vs baseline: 1.5948x; 1.5948x over previous
//
#include <hip/hip_runtime.h>
#include <hip/hip_fp16.h>

// MC-LSTM persistent recurrence, v15: v11 topology (8 b-slices x 7 unit-shards,
// 56 WGs x 512 thr, agent-scope relaxed tagged-data, double-buffered slab).
// Deltas vs v11: waves_per_eu(2,2) so B-fragments stay in VGPRs (v11 silently
// re-fetched 16KB/WG/step from L2/L3); per-wave 7-word gate on payload words
// (no extra hop); aX GEMM hoisted above the poll; B4 dropped (proof in round).

#define TT 2048
#define NBS 8
#define NUS 7
#define NWG 56

typedef _Float16 f16;
typedef _Float16 f16x8 __attribute__((ext_vector_type(8)));
typedef float f32x4 __attribute__((ext_vector_type(4)));

#define LD_RLX(p)   __hip_atomic_load((p), __ATOMIC_RELAXED, __HIP_MEMORY_SCOPE_AGENT)
#define ST_RLX(p,v) __hip_atomic_store((p), (v), __ATOMIC_RELAXED, __HIP_MEMORY_SCOPE_AGENT)

static __device__ __forceinline__ unsigned packf16(float v, unsigned tag) {
  f16 h = (f16)v;
  unsigned short s;
  __builtin_memcpy(&s, &h, 2);
  return ((unsigned)s << 16) | (tag & 0xffffu);
}
static __device__ __forceinline__ float unpackf16(unsigned u) {
  unsigned short s = (unsigned short)(u >> 16);
  f16 h;
  __builtin_memcpy(&h, &s, 2);
  return (float)h;
}
static __device__ __forceinline__ float f16bits(unsigned short s) {
  f16 h;
  __builtin_memcpy(&h, &s, 2);
  return (float)h;
}
static __device__ __forceinline__ unsigned short f16of(float v) {
  f16 h = (f16)v;
  unsigned short s;
  __builtin_memcpy(&s, &h, 2);
  return s;
}

// ---- ws layout (bytes) ----
#define OFF_WH   0u
#define SZ_WH    (97u * 8192u * 2u)                    // fp16 weights [unit][h][g]
#define OFF_SLAB ((OFF_WH + SZ_WH + 255u) & ~255u)     // [2][8 bs][7 us][1024] u32
#define SZ_SLAB  (2u * NBS * NUS * 1024u * 4u)
#define OFF_NS   (OFF_SLAB + SZ_SLAB)                  // [2][8 bs] tagged u32
#define SZ_NS    (2u * NBS * 4u)
#define ZERO_OFF OFF_SLAB
#define ZERO_LEN (SZ_SLAB + SZ_NS)

__global__ void prep_kernel(const float* __restrict__ Wi, const float* __restrict__ Wr,
                            const float* __restrict__ Wo, f16* __restrict__ Wh) {
  int idx = blockIdx.x * 256 + threadIdx.x;
  if (idx >= 97 * 8192) return;
  int g = idx & 127, h = (idx >> 7) & 63, r = idx >> 13;
  float v;
  if (r < 32)      v = Wi[g * 2048 + r * 64 + h];
  else if (r < 96) v = Wr[g * 4096 + (r - 32) * 64 + h];
  else             v = Wo[g * 64 + h];
  Wh[idx] = (f16)v;
}

__launch_bounds__(512)
__attribute__((amdgpu_waves_per_eu(2, 2)))  // 256-VGPR budget: Bf stays resident
__global__ void mclstm_kernel(const float* __restrict__ xm, const float* __restrict__ xa,
                              const float* __restrict__ bi, const float* __restrict__ br,
                              const float* __restrict__ bo, const f16* __restrict__ Wh,
                              unsigned* __restrict__ slab, unsigned* __restrict__ nslab,
                              float* __restrict__ out) {
  const int j = blockIdx.x, tid = threadIdx.x;
  const int us = j % NUS, bs = j / NUS;
  const int w = tid >> 6, l = tid & 63, lr = l & 15, lk = l >> 4;
  const bool isO = (us == 6);
  const bool isIWG = (us < 2);  // us 0,1 -> i-units 0..31; 2..5 -> r; 6 -> o

  __shared__ unsigned short craw[16][88];  // raw c bits (this b-slice), padded rows
  __shared__ float pslab[8][1024];         // per-wave contrib partials
  __shared__ float nredL[8];
  __shared__ float invS;

  for (int i = tid; i < 16 * 88; i += 512) (&craw[0][0])[i] = 0;
  if (tid == 0) invS = 0.f;

  // ---- persistent weights in registers: 2 units per wave (us6 -> o unit 96) ----
  f16x8 Bf[2][4][4];
  float bu[2][4];
#pragma unroll
  for (int un = 0; un < 2; ++un) {
    int u = isO ? 96 : us * 16 + 2 * w + un;
#pragma unroll
    for (int ht = 0; ht < 4; ++ht) {
      int col = ht * 16 + lr;
      bu[un][ht] = (u < 32) ? bi[u * 64 + col]
                 : (u < 96) ? br[(u - 32) * 64 + col] : bo[col];
#pragma unroll
      for (int kk = 0; kk < 4; ++kk)
        Bf[un][ht][kk] = *(const f16x8*)(Wh + (size_t)u * 8192 + col * 128 + kk * 32 + lk * 8);
    }
  }

  const size_t xoff = (size_t)(bs * 16 + lr) * 32 + lk * 8;
  f32x4 xA0 = *(const f32x4*)(xm + xoff), xA1 = *(const f32x4*)(xm + xoff + 4);
  f32x4 xB0 = *(const f32x4*)(xa + xoff), xB1 = *(const f32x4*)(xa + xoff + 4);
  __syncthreads();

  for (int t = 0; t <= TT; ++t) {
    // ---- phase 0 (t<TT): xw prefetch + aX GEMM hoisted ABOVE the poll ----
    float xw[2][4];
    f32x4 aX[2][4];
    if (t < TT) {
      if (isIWG) {
        const float* xmtp = xm + (size_t)t * 4096;
#pragma unroll
        for (int rr = 0; rr < 4; ++rr) {
          const size_t ro = (size_t)(bs * 16 + lk * 4 + rr) * 32 + us * 16 + 2 * w;
          xw[0][rr] = xmtp[ro];
          xw[1][rr] = xmtp[ro + 1];
        }
      }
      f16x8 A0, A1;
#pragma unroll
      for (int i = 0; i < 4; ++i) {
        A0[i] = (f16)xA0[i]; A0[4 + i] = (f16)xA1[i];
        A1[i] = (f16)xB0[i]; A1[4 + i] = (f16)xB1[i];
      }
      if (t + 1 < TT) {  // issue next-x loads; consumed next iteration
        const float* bx = xm + (size_t)(t + 1) * 4096 + xoff;
        const float* ba = xa + (size_t)(t + 1) * 4096 + xoff;
        xA0 = *(const f32x4*)bx; xA1 = *(const f32x4*)(bx + 4);
        xB0 = *(const f32x4*)ba; xB1 = *(const f32x4*)(ba + 4);
      }
      if (!isO || w == 0) {
#pragma unroll
        for (int un = 0; un < 2; ++un)
#pragma unroll
          for (int ht = 0; ht < 4; ++ht) {
            f32x4 a = (f32x4){0.f, 0.f, 0.f, 0.f};
            a = __builtin_amdgcn_mfma_f32_16x16x32_f16(A0, Bf[un][ht][0], a, 0, 0, 0);
            a = __builtin_amdgcn_mfma_f32_16x16x32_f16(A1, Bf[un][ht][1], a, 0, 0, 0);
            aX[un][ht] = a;
          }
      }
    }

    // ---- phase 1: gate + tag-verified sweep; local reduce; stage craw ----
    if (t > 0) {
      const unsigned want = (unsigned)t & 0xffffu;
      const unsigned* base = slab + ((size_t)(t & 1) * NBS + bs) * (NUS * 1024);
      // per-wave cheap gate: lanes 0..6 poll element 128*w of each column.
      // Same payload words (no extra hop) -> detection == data arrival; the
      // full sweep below re-verifies every word, so the gate is latency-only.
      {
        const unsigned* gp = base + l * 1024 + 128 * w;
        for (;;) {
          unsigned v = (l < NUS) ? LD_RLX(gp) : want;
          if (__all((int)((v & 0xffffu) == want))) break;
          __builtin_amdgcn_s_sleep(1);
        }
      }
      const int e0 = 2 * tid;
      unsigned pv[14];
      for (;;) {
#pragma unroll
        for (int c = 0; c < 7; ++c) {
          pv[c] = LD_RLX(base + c * 1024 + e0);
          pv[7 + c] = LD_RLX(base + c * 1024 + e0 + 1);
        }
        unsigned m = 0;
#pragma unroll
        for (int c = 0; c < 14; ++c) m |= (pv[c] ^ want) & 0xffffu;
        if (m == 0) break;
        __builtin_amdgcn_s_sleep(1);
      }
      float mn0 = 0.f, mn1 = 0.f;
#pragma unroll
      for (int c = 0; c < 6; ++c) {
        mn0 += unpackf16(pv[c]);
        mn1 += unpackf16(pv[7 + c]);
      }
      const float ov0 = unpackf16(pv[6]), ov1 = unpackf16(pv[13]);
      const float cn0 = (1.0f - ov0) * mn0, cn1 = (1.0f - ov1) * mn1;
      const unsigned short h0 = f16of(cn0), h1 = f16of(cn1);
      const int b = e0 >> 6, h = e0 & 63;
      craw[b][h] = h0;
      craw[b][h + 1] = h1;
      if (isO) {
        float ns = fabsf(f16bits(h0)) + fabsf(f16bits(h1));
        ns += __shfl_xor(ns, 1, 64);
        ns += __shfl_xor(ns, 2, 64);
        ns += __shfl_xor(ns, 4, 64);
        ns += __shfl_xor(ns, 8, 64);
        ns += __shfl_xor(ns, 16, 64);
        ns += __shfl_xor(ns, 32, 64);
        if (l == 0) nredL[w] = ns;
        __syncthreads();
        if (tid == 0) {
          float nsum = 0.f;
#pragma unroll
          for (int p = 0; p < 8; ++p) nsum += nredL[p];
          ST_RLX(nslab + (t & 1) * NBS + bs, packf16(nsum, (unsigned)t));
        }
        // out writes for step t-1 (fire-and-forget)
        const int bg = bs * 16 + b;
        out[(size_t)(t - 1) * 8192 + bg * 64 + h] = ov0 * mn0;
        out[(size_t)(t - 1) * 8192 + bg * 64 + h + 1] = ov1 * mn1;
        out[(size_t)(TT + t - 1) * 8192 + bg * 64 + h] = cn0;
        out[(size_t)(TT + t - 1) * 8192 + bg * 64 + h + 1] = cn1;
      }
    }
    if (t == TT) break;
    __syncthreads();  // B1: craw staged

    // ---- phase 3: c A-frags (raw c) + aC GEMM ----
    f16x8 A2, A3;
    {
      const unsigned short* cr = &craw[lr][0];
#pragma unroll
      for (int i = 0; i < 8; ++i) A2[i] = *(const f16*)&cr[lk * 8 + i];
#pragma unroll
      for (int i = 0; i < 8; ++i) A3[i] = *(const f16*)&cr[32 + lk * 8 + i];
    }
    f32x4 aC[2][4];
    if (!isO || w == 0) {
#pragma unroll
      for (int un = 0; un < 2; ++un)
#pragma unroll
        for (int ht = 0; ht < 4; ++ht) {
          f32x4 c = (f32x4){0.f, 0.f, 0.f, 0.f};
          c = __builtin_amdgcn_mfma_f32_16x16x32_f16(A2, Bf[un][ht][2], c, 0, 0, 0);
          c = __builtin_amdgcn_mfma_f32_16x16x32_f16(A3, Bf[un][ht][3], c, 0, 0, 0);
          aC[un][ht] = c;
        }
    }

    // ---- phase 4: wave0 polls the 8 norm words (overlapped with GEMM) ----
    if (t > 0 && w == 0) {
      const unsigned want = (unsigned)t & 0xffffu;
      const unsigned* nsb = nslab + (t & 1) * NBS;
      unsigned v;
      for (;;) {
        v = (l < NBS) ? LD_RLX(nsb + l) : want;
        if (__all((int)((v & 0xffffu) == want))) break;
        __builtin_amdgcn_s_sleep(1);
      }
      float ns = (l < NBS) ? unpackf16(v) : 0.f;
      ns += __shfl_xor(ns, 1, 64);
      ns += __shfl_xor(ns, 2, 64);
      ns += __shfl_xor(ns, 4, 64);
      if (l == 0) invS = __builtin_amdgcn_rcpf(ns + 1e-5f);
    }
    __syncthreads();  // B2: invS visible
    const float inv = invS;

    // ---- phase 5: epilogue z = aX + inv*aC + b ----
    if (!isO) {
      float contrib[4][4];
#pragma unroll
      for (int ht = 0; ht < 4; ++ht)
#pragma unroll
        for (int rr = 0; rr < 4; ++rr) contrib[ht][rr] = 0.f;
#pragma unroll
      for (int un = 0; un < 2; ++un) {
        const int kidx = us * 16 + 2 * w + un - 32;  // valid for r-units only
#pragma unroll
        for (int rr = 0; rr < 4; ++rr) {
          const int b = lk * 4 + rr;
          float s4[4], sum = 0.f;
#pragma unroll
          for (int ht = 0; ht < 4; ++ht) {
            float z = aX[un][ht][rr] + inv * aC[un][ht][rr] + bu[un][ht];
            float sg = __builtin_amdgcn_rcpf(1.0f + __expf(-z));
            s4[ht] = sg;
            sum += sg;
          }
          float r4 = sum;
          r4 += __shfl_xor(r4, 1, 64);
          r4 += __shfl_xor(r4, 2, 64);
          r4 += __shfl_xor(r4, 4, 64);
          r4 += __shfl_xor(r4, 8, 64);
          float wr = isIWG ? xw[un][rr] : f16bits(craw[b][kidx]);
          float sc = wr * __builtin_amdgcn_rcpf(fmaxf(r4, 1e-12f));
#pragma unroll
          for (int ht = 0; ht < 4; ++ht) contrib[ht][rr] += s4[ht] * sc;
        }
      }
#pragma unroll
      for (int ht = 0; ht < 4; ++ht)
#pragma unroll
        for (int rr = 0; rr < 4; ++rr)
          pslab[w][(lk * 4 + rr) * 64 + ht * 16 + lr] = contrib[ht][rr];
    } else if (w == 0) {
#pragma unroll
      for (int ht = 0; ht < 4; ++ht)
#pragma unroll
        for (int rr = 0; rr < 4; ++rr) {
          float z = aX[0][ht][rr] + inv * aC[0][ht][rr] + bu[0][ht];
          pslab[0][(lk * 4 + rr) * 64 + ht * 16 + lr] =
              __builtin_amdgcn_rcpf(1.0f + __expf(-z));
        }
    }
    __syncthreads();  // B3: pslab complete (also fences craw/pslab WAR chain)

    // ---- phase 6: intra-WG sum -> tagged column store (fire-and-forget) ----
    {
      const int e0 = 2 * tid;
      float v0, v1;
      if (!isO) {
        v0 = 0.f; v1 = 0.f;
#pragma unroll
        for (int p = 0; p < 8; ++p) {
          float2 pv2 = *(const float2*)&pslab[p][e0];
          v0 += pv2.x;
          v1 += pv2.y;
        }
      } else {
        float2 pv2 = *(const float2*)&pslab[0][e0];
        v0 = pv2.x;
        v1 = pv2.y;
      }
      const unsigned tg = (unsigned)(t + 1);
      unsigned* dst = slab + ((size_t)((t + 1) & 1) * NBS + bs) * (NUS * 1024) + us * 1024;
      ST_RLX(dst + e0, packf16(v0, tg));
      ST_RLX(dst + e0 + 1, packf16(v1, tg));
    }
    // no B4: B3 + downstream barriers already order all LDS reuse (see proof)
  }
}

extern "C" void kernel_launch(void* const* d_in, const int* in_sizes, int n_in,
                              void* d_out, int out_size, void* d_ws, size_t ws_size,
                              hipStream_t stream) {
  (void)in_sizes; (void)n_in; (void)out_size; (void)ws_size;
  const float* xm = (const float*)d_in[0];
  const float* xa = (const float*)d_in[1];
  const float* Wi = (const float*)d_in[2];
  const float* bi = (const float*)d_in[3];
  const float* Wr = (const float*)d_in[4];
  const float* br = (const float*)d_in[5];
  const float* Wo = (const float*)d_in[6];
  const float* bo = (const float*)d_in[7];

  char* ws = (char*)d_ws;
  f16* Wh         = (f16*)(ws + OFF_WH);
  unsigned* slab  = (unsigned*)(ws + OFF_SLAB);
  unsigned* nslab = (unsigned*)(ws + OFF_NS);

  // Tag hygiene across graph replays.
  hipMemsetAsync(ws + ZERO_OFF, 0, ZERO_LEN, stream);
  prep_kernel<<<(97 * 8192 + 255) / 256, 256, 0, stream>>>(Wi, Wr, Wo, Wh);
  mclstm_kernel<<<NWG, 512, 0, stream>>>(xm, xa, bi, br, bo, Wh, slab, nslab,
                                         (float*)d_out);
}